// Round 5
// baseline (8593.965 us; speedup 1.0000x reference)
//
#include <hip/hip_runtime.h>
#include <stdint.h>
#include <algorithm>

#define BATCH 8
#define NPTS 16384
#define NPOINT 1024
#define KNN 32
#define SAMPLE_NUM 10
#define SELN 7
#define SUBSET 29
#define RADIUS 0.2f
#define CAP 2048

// FPS multi-block decomposition
#define NG 8            // blocks (groups) per batch
#define FPS_THREADS 512
#define FPT (NPTS / NG / FPS_THREADS)   // points per thread = 4
static_assert(FPT * FPS_THREADS * NG == NPTS, "partition must cover all points");

// ---------------------------------------------------------------------------
// Host-side threefry2x32 replicating jax.random under the PARTITIONABLE
// implementation (jax_threefry_partitionable defaults True since JAX 0.4.36):
//   key(42) = (0,42)
//   fold_in(key,i)   = tf(key, (c0=0, c1=i))
//   split(folded)[1] = tf(folded, (c0=0, c1=1))
//   random_bits(subkey, 32, (32,)): lane j = tf(subkey, (0, j)), bits = o0^o1
//   permutation      = arange(32) stably sorted by bits ascending
// ---------------------------------------------------------------------------
struct PermTab { unsigned char p[SAMPLE_NUM][SUBSET]; };

static inline uint32_t rotl32h(uint32_t x, int d) { return (x << d) | (x >> (32 - d)); }

static void tf2x32(uint32_t k0, uint32_t k1, uint32_t c0, uint32_t c1,
                   uint32_t& o0, uint32_t& o1) {
    const uint32_t ks[3] = { k0, k1, k0 ^ k1 ^ 0x1BD11BDAu };
    uint32_t x0 = c0 + ks[0];
    uint32_t x1 = c1 + ks[1];
    static const int R[8] = {13, 15, 26, 6, 17, 29, 16, 24};
    for (int s = 0; s < 5; ++s) {
        const int* r = R + (s % 2) * 4;
        for (int j = 0; j < 4; ++j) {
            x0 += x1;
            x1 = rotl32h(x1, r[j]);
            x1 ^= x0;
        }
        x0 += ks[(s + 1) % 3];
        x1 += ks[(s + 2) % 3] + (uint32_t)(s + 1);
    }
    o0 = x0; o1 = x1;
}

static PermTab build_tab() {
    PermTab t;
    for (int i = 0; i < SAMPLE_NUM; ++i) {
        uint32_t f0, f1;
        tf2x32(0u, 42u, 0u, (uint32_t)i, f0, f1);
        uint32_t s0, s1;
        tf2x32(f0, f1, 0u, 1u, s0, s1);
        uint32_t bits[32];
        for (int j = 0; j < 32; ++j) {
            uint32_t o0, o1;
            tf2x32(s0, s1, 0u, (uint32_t)j, o0, o1);
            bits[j] = o0 ^ o1;
        }
        int perm[32];
        for (int j = 0; j < 32; ++j) perm[j] = j;
        std::stable_sort(perm, perm + 32, [&](int x, int y) {
            return bits[x] < bits[y];
        });
        for (int q = 0; q < SUBSET; ++q) t.p[i][q] = (unsigned char)perm[q];
    }
    return t;
}

// ---------------------------------------------------------------------------
// Kernel 1: FPS. r12 = r11 with the atomic ordering macros fixed
// (__ATOMIC_RELEASE/__ATOMIC_ACQUIRE; __HIP_MEMORY_ORDER_* doesn't exist).
// r10 post-mortem: three data placements (global remat / scratch spill / LDS)
// all landed at ~3900 cyc/iter with per-active-CU VALUBusy ~100% -> the 8
// active CUs are VALU-ISSUE bound; 248 CUs idle. Issue per SIMD = waves/SIMD
// x instrs/wave; only spreading the scan over more CUs reduces it.
// Structure: NG=8 blocks per batch x 512 threads x 4 pts/thread (coords+dd
// in registers -- 16 floats, no spill possible). Per iteration:
//   scan own 2048-pt shard -> wave DPP u64-max -> LDS skey -> barrier ->
//   block DPP max -> tid0 RELEASE-stores block key to comm[b][t][g] ->
//   all waves ACQUIRE-poll the 8 slots (one 64-B line, write-once per t,
//   zeroed by hipMemsetAsync before launch -> no ABA/reset protocol) ->
//   DPP max over slots -> identical global winner in every block ->
//   scalar s_load of winner coords. Max over u64 keys is associative and
//   the per-point arithmetic is untouched, so the selected winner is
//   bit-identical to the single-block version (rounds 3-10 numerics:
//   contract(off), (dx*dx+dy*dy)+dz*dz RNE, fminf, strict > ascending
//   index, key = dist_bits<<32 | (0xFFFFFFFF - global_p)).
// Only group 0 writes centers; each group writes its own sx shard.
// Co-residency: 64 blocks on 256 CUs -- all resident at dispatch; polling
// cannot deadlock. comm aliases the `grouped` ws region (knn overwrites it
// later in stream order).
// ---------------------------------------------------------------------------
#define REP4(M) M(0) M(1) M(2) M(3)

// u64 max across lanes, one DPP step. old-preserve (bound_ctrl=false,
// masks 0xf): lanes with invalid source keep their own key -> max no-op.
#define DPP_MAX_STEP(var, ctrl) { \
        const unsigned lo_ = (unsigned)(var); \
        const unsigned hi_ = (unsigned)((var) >> 32); \
        const unsigned olo_ = (unsigned)__builtin_amdgcn_update_dpp( \
            (int)lo_, (int)lo_, (ctrl), 0xf, 0xf, false); \
        const unsigned ohi_ = (unsigned)__builtin_amdgcn_update_dpp( \
            (int)hi_, (int)hi_, (ctrl), 0xf, 0xf, false); \
        const unsigned long long o_ = \
            ((unsigned long long)ohi_ << 32) | (unsigned long long)olo_; \
        (var) = (o_ > (var)) ? o_ : (var); }

__global__ __launch_bounds__(FPS_THREADS) void fps_kernel(const float* __restrict__ xyz,
                                                          float* __restrict__ centers,
                                                          float* __restrict__ sx,
                                                          unsigned long long* __restrict__ comm) {
#pragma clang fp contract(off)
    const int b = blockIdx.x & (NG - 1);   // batch (bid%8 -> same-XCD heuristic)
    const int g = blockIdx.x >> 3;         // group within batch
    const int tid = threadIdx.x;
    const int wv = tid >> 6;
    const int lane = tid & 63;
    const int p0 = g * (NPTS / NG);        // shard base: g*2048

    __shared__ unsigned long long skey[2][FPS_THREADS / 64];

    const float* base = xyz + (size_t)b * NPTS * 3;

#define P_DECL(i) float px##i, py##i, pz##i, dd##i;
    REP4(P_DECL)
#undef P_DECL

#define P_LOAD(i) { \
        const int p = p0 + (i) * FPS_THREADS + tid; \
        px##i = base[p * 3 + 0]; \
        py##i = base[p * 3 + 1]; \
        pz##i = base[p * 3 + 2]; \
        dd##i = 1e10f; \
        sx[(size_t)b * NPTS + p] = (px##i * px##i + py##i * py##i) + pz##i * pz##i; }
    REP4(P_LOAD)
#undef P_LOAD

    // Pin coords: an asm def cannot be rematerialized (r7 lesson). At 16
    // floats of pinned state the allocator has no spill incentive either.
#define P_PIN(i) asm volatile("" : "+v"(px##i), "+v"(py##i), "+v"(pz##i));
    REP4(P_PIN)
#undef P_PIN

    float cx = base[0], cy = base[1], cz = base[2];
    if (g == 0 && tid == 0) {
        float* dst = centers + (size_t)b * NPOINT * 3;
        dst[0] = cx; dst[1] = cy; dst[2] = cz;
    }

    for (int t = 1; t < NPOINT; ++t) {
        const int par = t & 1;
        float bv = -1.0f;
        int bi = 0;
        // ascending i with strict > keeps the smallest index on ties,
        // matching numpy argmax first-index semantics (verified r3-r10).
#define P_SCAN(i) { \
        const float dx = px##i - cx; \
        const float dy = py##i - cy; \
        const float dz = pz##i - cz; \
        const float d = (dx * dx + dy * dy) + dz * dz; \
        const float nd = fminf(dd##i, d); \
        dd##i = nd; \
        if (nd > bv) { bv = nd; bi = (i); } }
        REP4(P_SCAN)
#undef P_SCAN

        const unsigned bp = (unsigned)(p0 + (bi << 9) + tid);  // global index
        unsigned long long key =
            ((unsigned long long)__float_as_uint(bv) << 32) |
            (unsigned long long)(0xFFFFFFFFu - bp);

        // wave64 u64-max reduce in the VALU pipe (r8, verified):
        DPP_MAX_STEP(key, 0x111)   // row_shr:1
        DPP_MAX_STEP(key, 0x112)   // row_shr:2
        DPP_MAX_STEP(key, 0x114)   // row_shr:4
        DPP_MAX_STEP(key, 0x118)   // row_shr:8
        DPP_MAX_STEP(key, 0x142)   // row_bcast:15
        DPP_MAX_STEP(key, 0x143)   // row_bcast:31
        if (lane == 63) skey[par][wv] = key;
        __syncthreads();

        // block reduce over 8 wave slots: broadcast read + 3 row_shr steps
        // -> lane 7 holds the block max.
        unsigned long long kk = skey[par][lane & 7];
        DPP_MAX_STEP(kk, 0x111)
        DPP_MAX_STEP(kk, 0x112)
        DPP_MAX_STEP(kk, 0x114)
        const unsigned bk_lo = (unsigned)__builtin_amdgcn_readlane((int)(unsigned)kk, 7);
        const unsigned bk_hi = (unsigned)__builtin_amdgcn_readlane((int)(unsigned)(kk >> 32), 7);
        const unsigned long long bk =
            ((unsigned long long)bk_hi << 32) | (unsigned long long)bk_lo;

        unsigned long long* slots = comm + ((size_t)b * NPOINT + (size_t)t) * NG;
        if (tid == 0) {
            __hip_atomic_store(&slots[g], bk, __ATOMIC_RELEASE,
                               __HIP_MEMORY_SCOPE_AGENT);
        }

        // acquire-poll all 8 group slots (write-once per t, nonzero when
        // ready: key low half = 0xFFFFFFFF - p > 0 always).
        unsigned long long k2;
        for (;;) {
            k2 = __hip_atomic_load(&slots[lane & 7], __ATOMIC_ACQUIRE,
                                   __HIP_MEMORY_SCOPE_AGENT);
            if (!__ballot(k2 == 0ULL)) break;
            __builtin_amdgcn_s_sleep(1);
        }
        DPP_MAX_STEP(k2, 0x111)
        DPP_MAX_STEP(k2, 0x112)
        DPP_MAX_STEP(k2, 0x114)

        const unsigned klo = (unsigned)__builtin_amdgcn_readlane((int)(unsigned)k2, 7);
        const int ps = (int)(0xFFFFFFFFu - klo);   // scalar winner index
        const float* sp = base + (size_t)ps * 3;
        cx = sp[0]; cy = sp[1]; cz = sp[2];        // scalar loads (L2)

        if (g == 0 && tid == 0) {
            float* dst = centers + ((size_t)b * NPOINT + t) * 3;
            dst[0] = cx; dst[1] = cy; dst[2] = cz;
        }
    }
}

// ---------------------------------------------------------------------------
// Kernel 2: exact KNN top-32 (ascending d2, ties -> lower index), one block
// per center. Radix-select on the monotone uint key of
// d2 = (|c|^2 + |x|^2) - 2*dot (reference association, _rn ops), then exact
// O(L^2) rank of the candidate superset. Writes grouped coords rank-sorted.
// (unchanged from the passing round-3 kernel)
// ---------------------------------------------------------------------------
__global__ __launch_bounds__(256) void knn_kernel(const float* __restrict__ xyz,
                                                  const float* __restrict__ centers,
                                                  const float* __restrict__ sx,
                                                  float* __restrict__ grouped) {
    const int bs = blockIdx.x;
    const int b = bs >> 10;
    const int tid = threadIdx.x;

    __shared__ unsigned hist[2048];
    __shared__ unsigned ckey[CAP];
    __shared__ int cidx[CAP];
    __shared__ int cnt;
    __shared__ int bstar;

    const float cx = centers[(size_t)bs * 3 + 0];
    const float cy = centers[(size_t)bs * 3 + 1];
    const float cz = centers[(size_t)bs * 3 + 2];
    const float sc = __fadd_rn(__fadd_rn(__fmul_rn(cx, cx), __fmul_rn(cy, cy)),
                               __fmul_rn(cz, cz));

    for (int q = tid; q < 2048; q += 256) hist[q] = 0;
    if (tid == 0) cnt = 0;
    __syncthreads();

    const float* base = xyz + (size_t)b * NPTS * 3;
    const float* sxb = sx + (size_t)b * NPTS;

    for (int j = tid; j < NPTS; j += 256) {
        float xx = base[j * 3 + 0], xy = base[j * 3 + 1], xz = base[j * 3 + 2];
        float dot = __fadd_rn(__fadd_rn(__fmul_rn(cx, xx), __fmul_rn(cy, xy)),
                              __fmul_rn(cz, xz));
        float d2 = __fsub_rn(__fadd_rn(sc, sxb[j]), __fmul_rn(2.0f, dot));
        unsigned u = __float_as_uint(d2);
        unsigned key = u ^ ((u & 0x80000000u) ? 0xFFFFFFFFu : 0x80000000u);
        atomicAdd(&hist[key >> 21], 1u);
    }
    __syncthreads();

    if (tid < 64) {
        unsigned sum = 0;
#pragma unroll
        for (int q = 0; q < 32; ++q) sum += hist[tid * 32 + q];
        unsigned incl = sum;
        for (int d = 1; d < 64; d <<= 1) {
            unsigned o = __shfl_up(incl, d, 64);
            if (tid >= d) incl += o;
        }
        unsigned long long m = __ballot(incl >= 32u);
        int L = __ffsll(m) - 1;
        if (tid == L) {
            unsigned cum = incl - sum;
            int bb = L * 32 + 31;
            for (int q = 0; q < 32; ++q) {
                cum += hist[L * 32 + q];
                if (cum >= 32u) { bb = L * 32 + q; break; }
            }
            bstar = bb;
        }
    }
    __syncthreads();

    const int bst = bstar;
    for (int j = tid; j < NPTS; j += 256) {
        float xx = base[j * 3 + 0], xy = base[j * 3 + 1], xz = base[j * 3 + 2];
        float dot = __fadd_rn(__fadd_rn(__fmul_rn(cx, xx), __fmul_rn(cy, xy)),
                              __fmul_rn(cz, xz));
        float d2 = __fsub_rn(__fadd_rn(sc, sxb[j]), __fmul_rn(2.0f, dot));
        unsigned u = __float_as_uint(d2);
        unsigned key = u ^ ((u & 0x80000000u) ? 0xFFFFFFFFu : 0x80000000u);
        if ((int)(key >> 21) <= bst) {
            int pos = atomicAdd(&cnt, 1);
            if (pos < CAP) { ckey[pos] = key; cidx[pos] = j; }
        }
    }
    __syncthreads();

    const int L2 = min(cnt, CAP);
    for (int c = tid; c < L2; c += 256) {
        const unsigned k = ckey[c];
        const int id = cidx[c];
        int rank = 0;
        for (int m2 = 0; m2 < L2; ++m2) {
            const unsigned km = ckey[m2];
            rank += (km < k || (km == k && cidx[m2] < id)) ? 1 : 0;
        }
        if (rank < KNN) {
            float* dst = grouped + ((size_t)bs * KNN + rank) * 3;
            dst[0] = base[id * 3 + 0];
            dst[1] = base[id * 3 + 1];
            dst[2] = base[id * 3 + 2];
        }
    }
}

// ---------------------------------------------------------------------------
// Kernel 3: robust centroid + features, numpy f32 rounding (no fma; matching
// summation orders). (unchanged from the passing round-3 kernel)
// ---------------------------------------------------------------------------
__global__ __launch_bounds__(256) void feat_kernel(const float* __restrict__ centers,
                                                   const float* __restrict__ grouped,
                                                   float* __restrict__ out,
                                                   PermTab tab) {
    const int bs = blockIdx.x * 256 + threadIdx.x;
    if (bs >= BATCH * NPOINT) return;

    const float* g = grouped + (size_t)bs * KNN * 3;

    float clx[SAMPLE_NUM], cly[SAMPLE_NUM], clz[SAMPLE_NUM];
    for (int i = 0; i < SAMPLE_NUM; ++i) {
        float sxm = 0.f, sym = 0.f, szm = 0.f;
        for (int j = 0; j < SUBSET; ++j) {
            const int p = tab.p[i][j];
            sxm = __fadd_rn(sxm, g[p * 3 + 0]);
            sym = __fadd_rn(sym, g[p * 3 + 1]);
            szm = __fadd_rn(szm, g[p * 3 + 2]);
        }
        clx[i] = __fdiv_rn(sxm, 29.0f);
        cly[i] = __fdiv_rn(sym, 29.0f);
        clz[i] = __fdiv_rn(szm, 29.0f);
    }

    float sq[SAMPLE_NUM];
#pragma unroll
    for (int i = 0; i < SAMPLE_NUM; ++i)
        sq[i] = __fadd_rn(__fadd_rn(__fmul_rn(clx[i], clx[i]), __fmul_rn(cly[i], cly[i])),
                          __fmul_rn(clz[i], clz[i]));

    float ps[SAMPLE_NUM];
#pragma unroll
    for (int i = 0; i < SAMPLE_NUM; ++i) {
        float pd[SAMPLE_NUM];
#pragma unroll
        for (int j = 0; j < SAMPLE_NUM; ++j) {
            float dot = __fadd_rn(__fadd_rn(__fmul_rn(clx[i], clx[j]), __fmul_rn(cly[i], cly[j])),
                                  __fmul_rn(clz[i], clz[j]));
            pd[j] = __fsub_rn(__fadd_rn(sq[i], sq[j]), __fmul_rn(2.0f, dot));
        }
        float res = __fadd_rn(__fadd_rn(__fadd_rn(pd[0], pd[1]), __fadd_rn(pd[2], pd[3])),
                              __fadd_rn(__fadd_rn(pd[4], pd[5]), __fadd_rn(pd[6], pd[7])));
        res = __fadd_rn(res, pd[8]);
        res = __fadd_rn(res, pd[9]);
        ps[i] = res;
    }

    int rnk[SAMPLE_NUM];
#pragma unroll
    for (int j = 0; j < SAMPLE_NUM; ++j) {
        int r = 0;
#pragma unroll
        for (int m = 0; m < SAMPLE_NUM; ++m)
            r += (ps[m] < ps[j] || (ps[m] == ps[j] && m < j)) ? 1 : 0;
        rnk[j] = r;
    }

    float csx = 0.f, csy = 0.f, csz = 0.f;
    for (int r = 0; r < SELN; ++r) {
#pragma unroll
        for (int j = 0; j < SAMPLE_NUM; ++j) {
            if (rnk[j] == r) {
                csx = __fadd_rn(csx, clx[j]);
                csy = __fadd_rn(csy, cly[j]);
                csz = __fadd_rn(csz, clz[j]);
            }
        }
    }
    const float ccx = __fdiv_rn(csx, 7.0f);
    const float ccy = __fdiv_rn(csy, 7.0f);
    const float ccz = __fdiv_rn(csz, 7.0f);

    const float nx = centers[(size_t)bs * 3 + 0];
    const float ny = centers[(size_t)bs * 3 + 1];
    const float nz = centers[(size_t)bs * 3 + 2];

    const float ref_norm = __fsqrt_rn(__fadd_rn(
        __fadd_rn(__fmul_rn(nx, nx), __fmul_rn(ny, ny)), __fmul_rn(nz, nz)));
    const float den = __fadd_rn(ref_norm, 1e-4f);
    const float ux = __fdiv_rn(nx, den), uy = __fdiv_rn(ny, den), uz = __fdiv_rn(nz, den);
    const float ix = __fadd_rn(__fmul_rn(RADIUS, ux), nx);
    const float iy = __fadd_rn(__fmul_rn(RADIUS, uy), ny);
    const float iz = __fadd_rn(__fmul_rn(RADIUS, uz), nz);

    const float crvx = __fsub_rn(nx, ccx), crvy = __fsub_rn(ny, ccy), crvz = __fsub_rn(nz, ccz);
    const float crd = __fsqrt_rn(__fadd_rn(
        __fadd_rn(__fmul_rn(crvx, crvx), __fmul_rn(crvy, crvy)), __fmul_rn(crvz, crvz)));
    const float civx = __fsub_rn(ix, ccx), civy = __fsub_rn(iy, ccy), civz = __fsub_rn(iz, ccz);
    const float cid = __fsqrt_rn(__fadd_rn(
        __fadd_rn(__fmul_rn(civx, civx), __fmul_rn(civy, civy)), __fmul_rn(civz, civz)));
    const float dot = __fadd_rn(__fadd_rn(__fmul_rn(crvx, civx), __fmul_rn(crvy, civy)),
                                __fmul_rn(crvz, civz));
    const float ang_rci = __fdiv_rn(dot, __fadd_rn(__fmul_rn(crd, cid), 1e-6f));

    const float irvx = __fsub_rn(nx, ix), irvy = __fsub_rn(ny, iy), irvz = __fsub_rn(nz, iz);
    const float icvx = __fsub_rn(ccx, ix), icvy = __fsub_rn(ccy, iy), icvz = __fsub_rn(ccz, iz);
    const float dot2 = __fadd_rn(__fadd_rn(__fmul_rn(irvx, icvx), __fmul_rn(irvy, icvy)),
                                 __fmul_rn(irvz, icvz));
    const float ang_ric = __fdiv_rn(dot2, __fadd_rn(__fmul_rn(RADIUS, cid), 1e-6f));

    float* o = out + (size_t)bs * 5;
    o[0] = ref_norm;
    o[1] = crd;
    o[2] = cid;
    o[3] = ang_rci;
    o[4] = ang_ric;
}

// ---------------------------------------------------------------------------
extern "C" void kernel_launch(void* const* d_in, const int* in_sizes, int n_in,
                              void* d_out, int out_size, void* d_ws, size_t ws_size,
                              hipStream_t stream) {
    const float* xyz = (const float*)d_in[0];
    float* out = (float*)d_out;

    float* centers = (float*)d_ws;                       // B*NPOINT*3
    float* sx = centers + (size_t)BATCH * NPOINT * 3;    // B*N
    float* grouped = sx + (size_t)BATCH * NPTS;          // B*NPOINT*K*3

    // FPS comm slots alias `grouped`: fps finishes with them before knn
    // writes grouped (stream order). 8*1024*8*8 B = 512 KB <= 3 MB.
    unsigned long long* comm = (unsigned long long*)grouped;

    static PermTab tab = build_tab();  // deterministic, host-only

    (void)hipMemsetAsync(comm, 0,
                         (size_t)BATCH * NPOINT * NG * sizeof(unsigned long long),
                         stream);
    fps_kernel<<<BATCH * NG, FPS_THREADS, 0, stream>>>(xyz, centers, sx, comm);
    knn_kernel<<<BATCH * NPOINT, 256, 0, stream>>>(xyz, centers, sx, grouped);
    feat_kernel<<<(BATCH * NPOINT + 255) / 256, 256, 0, stream>>>(centers, grouped, out, tab);
}

// Round 6
// 1992.024 us; speedup vs baseline: 4.3142x; 4.3142x over previous
//
#include <hip/hip_runtime.h>
#include <stdint.h>
#include <algorithm>

#define BATCH 8
#define NPTS 16384
#define NPOINT 1024
#define KNN 32
#define SAMPLE_NUM 10
#define SELN 7
#define SUBSET 29
#define RADIUS 0.2f
#define CAP 2048

typedef float f32x2 __attribute__((ext_vector_type(2)));
typedef float f32x4 __attribute__((ext_vector_type(4)));

// ---------------------------------------------------------------------------
// Host-side threefry2x32 replicating jax.random under the PARTITIONABLE
// implementation (jax_threefry_partitionable defaults True since JAX 0.4.36):
//   key(42) = (0,42)
//   fold_in(key,i)   = tf(key, (c0=0, c1=i))
//   split(folded)[1] = tf(folded, (c0=0, c1=1))
//   random_bits(subkey, 32, (32,)): lane j = tf(subkey, (0, j)), bits = o0^o1
//   permutation      = arange(32) stably sorted by bits ascending
// ---------------------------------------------------------------------------
struct PermTab { unsigned char p[SAMPLE_NUM][SUBSET]; };

static inline uint32_t rotl32h(uint32_t x, int d) { return (x << d) | (x >> (32 - d)); }

static void tf2x32(uint32_t k0, uint32_t k1, uint32_t c0, uint32_t c1,
                   uint32_t& o0, uint32_t& o1) {
    const uint32_t ks[3] = { k0, k1, k0 ^ k1 ^ 0x1BD11BDAu };
    uint32_t x0 = c0 + ks[0];
    uint32_t x1 = c1 + ks[1];
    static const int R[8] = {13, 15, 26, 6, 17, 29, 16, 24};
    for (int s = 0; s < 5; ++s) {
        const int* r = R + (s % 2) * 4;
        for (int j = 0; j < 4; ++j) {
            x0 += x1;
            x1 = rotl32h(x1, r[j]);
            x1 ^= x0;
        }
        x0 += ks[(s + 1) % 3];
        x1 += ks[(s + 2) % 3] + (uint32_t)(s + 1);
    }
    o0 = x0; o1 = x1;
}

static PermTab build_tab() {
    PermTab t;
    for (int i = 0; i < SAMPLE_NUM; ++i) {
        uint32_t f0, f1;
        tf2x32(0u, 42u, 0u, (uint32_t)i, f0, f1);
        uint32_t s0, s1;
        tf2x32(f0, f1, 0u, 1u, s0, s1);
        uint32_t bits[32];
        for (int j = 0; j < 32; ++j) {
            uint32_t o0, o1;
            tf2x32(s0, s1, 0u, (uint32_t)j, o0, o1);
            bits[j] = o0 ^ o1;
        }
        int perm[32];
        for (int j = 0; j < 32; ++j) perm[j] = j;
        std::stable_sort(perm, perm + 32, [&](int x, int y) {
            return bits[x] < bits[y];
        });
        for (int q = 0; q < SUBSET; ++q) t.p[i][q] = (unsigned char)perm[q];
    }
    return t;
}

// ---------------------------------------------------------------------------
// Kernel 1: FPS. r13: single-block-per-batch is STRUCTURAL (r12 measured
// cross-block per-iter sync at ~7 us/iter -- 4x the whole iteration; FPS's
// 1023 dependent steps cannot amortize XCD-coherence round trips). The only
// lever left is VALU issue count per SIMD (per-CU VALUBusy ~100% in r10).
// Cuts vs r10 (~same structure, fewer ops):
//  - point-PAIR packed math: v_pk_sub/mul/add on f32x2 halves -- per-element
//    RNE is bit-identical to the scalar sequence (dx*dx+dy*dy)+dz*dz.
//    ~12 -> ~8 VALU/point.
//  - split reduce: f32 wave-max via 6 DPP-fusable v_max_f32 steps (vs u64
//    cmp+cndmask chains that cannot DPP-fuse), then u32 tie-break max of
//    (bv==wmax ? ~p : 0). Block phase the same on (float-bits, ~p) u32
//    pairs; float bits of non-negative floats are u32-monotone, so the
//    winner is bit-identical to the u64-key versions of r8-r12.
//  - (x,y) pairs in LDS, one ds_read_b128 per pair (128 KB, conflict-free
//    16B-consecutive pattern); z pairs + dd pairs in VGPRs (~62 live --
//    r10 proved this footprint does not spill at 1024 thr).
// Numerics: contract(off), RNE adds/muls in reference order, fminf exact,
// strict > ascending-index per-thread argmax (j asc, lo before hi = global
// p ascending), cross-lane/block tie-break by max ~p = min p. One
// barrier/iter; parity double-buffered per-wave slots.
// ---------------------------------------------------------------------------
#define REP8(M) M(0) M(1) M(2) M(3) M(4) M(5) M(6) M(7)

// f32 max across lanes, one DPP step (fusable to v_max_f32_dpp).
// old-preserve: invalid-source lanes keep own value -> max no-op.
#define DPP_FMAX_STEP(v, ctrl) { \
        const int t_ = __builtin_amdgcn_update_dpp( \
            __float_as_int(v), __float_as_int(v), (ctrl), 0xf, 0xf, false); \
        (v) = fmaxf((v), __int_as_float(t_)); }

// u32 max across lanes, one DPP step (fusable to v_max_u32_dpp).
#define DPP_UMAX_STEP(v, ctrl) { \
        const unsigned t_ = (unsigned)__builtin_amdgcn_update_dpp( \
            (int)(v), (int)(v), (ctrl), 0xf, 0xf, false); \
        (v) = (t_ > (v)) ? t_ : (v); }

__global__ __launch_bounds__(1024) void fps_kernel(const float* __restrict__ xyz,
                                                   float* __restrict__ centers,
                                                   float* __restrict__ sqout) {
#pragma clang fp contract(off)
    const int b = blockIdx.x;
    const int tid = threadIdx.x;
    const int wv = tid >> 6;
    const int lane = tid & 63;

    __shared__ f32x4 sPair[NPTS / 2];          // 128 KB: {x0,x1,y0,y1} per pair
    __shared__ unsigned skhi[2][16];           // per-wave wmax float bits
    __shared__ unsigned sklo[2][16];           // per-wave max ~p

    const float* base = xyz + (size_t)b * NPTS * 3;

#define P_DECL(j) f32x2 pz2##j, dd2##j;
    REP8(P_DECL)
#undef P_DECL

    // pair q = j*1024+tid holds points {2q, 2q+1}; floats at base[6q..6q+5]
#define P_LOAD(j) { \
        const int q = (j) * 1024 + tid; \
        const f32x2 a = *(const f32x2*)&base[6 * q]; \
        const f32x2 b2 = *(const f32x2*)&base[6 * q + 2]; \
        const f32x2 c = *(const f32x2*)&base[6 * q + 4]; \
        const f32x2 px2 = (f32x2){a.x, b2.y}; \
        const f32x2 py2 = (f32x2){a.y, c.x}; \
        pz2##j = (f32x2){b2.x, c.y}; \
        dd2##j = (f32x2){1e10f, 1e10f}; \
        sPair[q] = (f32x4){px2.x, px2.y, py2.x, py2.y}; \
        const f32x2 xx = px2 * px2, yy = py2 * py2, zz = pz2##j * pz2##j; \
        const f32x2 s1 = xx + yy; \
        const f32x2 dsq = s1 + zz; \
        *(f32x2*)&sqout[(size_t)b * NPTS + 2 * q] = dsq; }
    REP8(P_LOAD)
#undef P_LOAD

    // Pin z pairs: asm defs cannot be rematerialized (r7 lesson).
#define P_PIN(j) asm volatile("" : "+v"(pz2##j));
    REP8(P_PIN)
#undef P_PIN

    float cx = base[0], cy = base[1], cz = base[2];
    if (tid == 0) {
        float* dst = centers + (size_t)b * NPOINT * 3;
        dst[0] = cx; dst[1] = cy; dst[2] = cz;
    }
    __syncthreads();   // sPair seeded

    for (int t = 1; t < NPOINT; ++t) {
        const int par = t & 1;
        const f32x2 ccx2 = (f32x2){cx, cx};
        const f32x2 ccy2 = (f32x2){cy, cy};
        const f32x2 ccz2 = (f32x2){cz, cz};
        float bv = -1.0f;
        unsigned bidx = 0;
        // ascending (j, lo->hi) = ascending global p for this tid; strict >
        // keeps smallest p on ties (numpy argmax first-index, verified r3+).
#define P_SCAN(j) { \
        const f32x4 vv = sPair[(j) * 1024 + tid]; \
        const f32x2 dx = (f32x2){vv.x, vv.y} - ccx2; \
        const f32x2 dy = (f32x2){vv.z, vv.w} - ccy2; \
        const f32x2 dz = pz2##j - ccz2; \
        const f32x2 xx = dx * dx; \
        const f32x2 yy = dy * dy; \
        const f32x2 zz = dz * dz; \
        const f32x2 ss = xx + yy; \
        const f32x2 d = ss + zz; \
        const float nd0 = fminf(dd2##j.x, d.x); \
        const float nd1 = fminf(dd2##j.y, d.y); \
        dd2##j.x = nd0; dd2##j.y = nd1; \
        if (nd0 > bv) { bv = nd0; bidx = (j) * 2; } \
        if (nd1 > bv) { bv = nd1; bidx = (j) * 2 + 1; } }
        REP8(P_SCAN)
#undef P_SCAN

        // wave f32-max -> lane 63 (row_shr 1/2/4/8, row_bcast 15/31)
        float r = bv;
        DPP_FMAX_STEP(r, 0x111)
        DPP_FMAX_STEP(r, 0x112)
        DPP_FMAX_STEP(r, 0x114)
        DPP_FMAX_STEP(r, 0x118)
        DPP_FMAX_STEP(r, 0x142)
        DPP_FMAX_STEP(r, 0x143)
        const float wmax = __int_as_float(
            __builtin_amdgcn_readlane(__float_as_int(r), 63));

        // global point index p = j*2048 + 2*tid + h  (bidx = 2j+h)
        const unsigned p = ((bidx >> 1) << 11) + ((unsigned)tid << 1) + (bidx & 1);
        unsigned uk = (bv == wmax) ? ~p : 0u;   // max ~p = min p among ties
        DPP_UMAX_STEP(uk, 0x111)
        DPP_UMAX_STEP(uk, 0x112)
        DPP_UMAX_STEP(uk, 0x114)
        DPP_UMAX_STEP(uk, 0x118)
        DPP_UMAX_STEP(uk, 0x142)
        DPP_UMAX_STEP(uk, 0x143)

        if (lane == 63) {
            skhi[par][wv] = __float_as_uint(r);   // r == wave max here
            sklo[par][wv] = uk;
        }
        __syncthreads();

        // block phase over 16 wave slots (broadcast reads, conflict-free):
        // u32 max of float bits (monotone for >=0), then ~p among equal.
        const unsigned myhi = skhi[par][lane & 15];
        const unsigned mylo = sklo[par][lane & 15];
        unsigned h2 = myhi;
        DPP_UMAX_STEP(h2, 0x111)
        DPP_UMAX_STEP(h2, 0x112)
        DPP_UMAX_STEP(h2, 0x114)
        DPP_UMAX_STEP(h2, 0x118)
        const unsigned shi = (unsigned)__builtin_amdgcn_readlane((int)h2, 15);
        unsigned c2 = (myhi == shi) ? mylo : 0u;
        DPP_UMAX_STEP(c2, 0x111)
        DPP_UMAX_STEP(c2, 0x112)
        DPP_UMAX_STEP(c2, 0x114)
        DPP_UMAX_STEP(c2, 0x118)
        const unsigned slo = (unsigned)__builtin_amdgcn_readlane((int)c2, 15);
        const int ps = (int)(~slo);               // winner global index

        // winner coords: x,y from LDS (uniform broadcast), z from global L2
        const float* wrow = (const float*)&sPair[ps >> 1];
        cx = wrow[ps & 1];
        cy = wrow[2 + (ps & 1)];
        cz = base[(size_t)ps * 3 + 2];

        if (tid == 0) {
            float* dst = centers + ((size_t)b * NPOINT + t) * 3;
            dst[0] = cx; dst[1] = cy; dst[2] = cz;
        }
    }
}

// ---------------------------------------------------------------------------
// Kernel 2: exact KNN top-32 (ascending d2, ties -> lower index), one block
// per center. Radix-select on the monotone uint key of
// d2 = (|c|^2 + |x|^2) - 2*dot (reference association, _rn ops), then exact
// O(L^2) rank of the candidate superset. Writes grouped coords rank-sorted.
// (unchanged from the passing round-3 kernel)
// ---------------------------------------------------------------------------
__global__ __launch_bounds__(256) void knn_kernel(const float* __restrict__ xyz,
                                                  const float* __restrict__ centers,
                                                  const float* __restrict__ sx,
                                                  float* __restrict__ grouped) {
    const int bs = blockIdx.x;
    const int b = bs >> 10;
    const int tid = threadIdx.x;

    __shared__ unsigned hist[2048];
    __shared__ unsigned ckey[CAP];
    __shared__ int cidx[CAP];
    __shared__ int cnt;
    __shared__ int bstar;

    const float cx = centers[(size_t)bs * 3 + 0];
    const float cy = centers[(size_t)bs * 3 + 1];
    const float cz = centers[(size_t)bs * 3 + 2];
    const float sc = __fadd_rn(__fadd_rn(__fmul_rn(cx, cx), __fmul_rn(cy, cy)),
                               __fmul_rn(cz, cz));

    for (int q = tid; q < 2048; q += 256) hist[q] = 0;
    if (tid == 0) cnt = 0;
    __syncthreads();

    const float* base = xyz + (size_t)b * NPTS * 3;
    const float* sxb = sx + (size_t)b * NPTS;

    for (int j = tid; j < NPTS; j += 256) {
        float xx = base[j * 3 + 0], xy = base[j * 3 + 1], xz = base[j * 3 + 2];
        float dot = __fadd_rn(__fadd_rn(__fmul_rn(cx, xx), __fmul_rn(cy, xy)),
                              __fmul_rn(cz, xz));
        float d2 = __fsub_rn(__fadd_rn(sc, sxb[j]), __fmul_rn(2.0f, dot));
        unsigned u = __float_as_uint(d2);
        unsigned key = u ^ ((u & 0x80000000u) ? 0xFFFFFFFFu : 0x80000000u);
        atomicAdd(&hist[key >> 21], 1u);
    }
    __syncthreads();

    if (tid < 64) {
        unsigned sum = 0;
#pragma unroll
        for (int q = 0; q < 32; ++q) sum += hist[tid * 32 + q];
        unsigned incl = sum;
        for (int d = 1; d < 64; d <<= 1) {
            unsigned o = __shfl_up(incl, d, 64);
            if (tid >= d) incl += o;
        }
        unsigned long long m = __ballot(incl >= 32u);
        int L = __ffsll(m) - 1;
        if (tid == L) {
            unsigned cum = incl - sum;
            int bb = L * 32 + 31;
            for (int q = 0; q < 32; ++q) {
                cum += hist[L * 32 + q];
                if (cum >= 32u) { bb = L * 32 + q; break; }
            }
            bstar = bb;
        }
    }
    __syncthreads();

    const int bst = bstar;
    for (int j = tid; j < NPTS; j += 256) {
        float xx = base[j * 3 + 0], xy = base[j * 3 + 1], xz = base[j * 3 + 2];
        float dot = __fadd_rn(__fadd_rn(__fmul_rn(cx, xx), __fmul_rn(cy, xy)),
                              __fmul_rn(cz, xz));
        float d2 = __fsub_rn(__fadd_rn(sc, sxb[j]), __fmul_rn(2.0f, dot));
        unsigned u = __float_as_uint(d2);
        unsigned key = u ^ ((u & 0x80000000u) ? 0xFFFFFFFFu : 0x80000000u);
        if ((int)(key >> 21) <= bst) {
            int pos = atomicAdd(&cnt, 1);
            if (pos < CAP) { ckey[pos] = key; cidx[pos] = j; }
        }
    }
    __syncthreads();

    const int L2 = min(cnt, CAP);
    for (int c = tid; c < L2; c += 256) {
        const unsigned k = ckey[c];
        const int id = cidx[c];
        int rank = 0;
        for (int m2 = 0; m2 < L2; ++m2) {
            const unsigned km = ckey[m2];
            rank += (km < k || (km == k && cidx[m2] < id)) ? 1 : 0;
        }
        if (rank < KNN) {
            float* dst = grouped + ((size_t)bs * KNN + rank) * 3;
            dst[0] = base[id * 3 + 0];
            dst[1] = base[id * 3 + 1];
            dst[2] = base[id * 3 + 2];
        }
    }
}

// ---------------------------------------------------------------------------
// Kernel 3: robust centroid + features, numpy f32 rounding (no fma; matching
// summation orders). (unchanged from the passing round-3 kernel)
// ---------------------------------------------------------------------------
__global__ __launch_bounds__(256) void feat_kernel(const float* __restrict__ centers,
                                                   const float* __restrict__ grouped,
                                                   float* __restrict__ out,
                                                   PermTab tab) {
    const int bs = blockIdx.x * 256 + threadIdx.x;
    if (bs >= BATCH * NPOINT) return;

    const float* g = grouped + (size_t)bs * KNN * 3;

    float clx[SAMPLE_NUM], cly[SAMPLE_NUM], clz[SAMPLE_NUM];
    for (int i = 0; i < SAMPLE_NUM; ++i) {
        float sxm = 0.f, sym = 0.f, szm = 0.f;
        for (int j = 0; j < SUBSET; ++j) {
            const int p = tab.p[i][j];
            sxm = __fadd_rn(sxm, g[p * 3 + 0]);
            sym = __fadd_rn(sym, g[p * 3 + 1]);
            szm = __fadd_rn(szm, g[p * 3 + 2]);
        }
        clx[i] = __fdiv_rn(sxm, 29.0f);
        cly[i] = __fdiv_rn(sym, 29.0f);
        clz[i] = __fdiv_rn(szm, 29.0f);
    }

    float sq[SAMPLE_NUM];
#pragma unroll
    for (int i = 0; i < SAMPLE_NUM; ++i)
        sq[i] = __fadd_rn(__fadd_rn(__fmul_rn(clx[i], clx[i]), __fmul_rn(cly[i], cly[i])),
                          __fmul_rn(clz[i], clz[i]));

    float ps[SAMPLE_NUM];
#pragma unroll
    for (int i = 0; i < SAMPLE_NUM; ++i) {
        float pd[SAMPLE_NUM];
#pragma unroll
        for (int j = 0; j < SAMPLE_NUM; ++j) {
            float dot = __fadd_rn(__fadd_rn(__fmul_rn(clx[i], clx[j]), __fmul_rn(cly[i], cly[j])),
                                  __fmul_rn(clz[i], clz[j]));
            pd[j] = __fsub_rn(__fadd_rn(sq[i], sq[j]), __fmul_rn(2.0f, dot));
        }
        float res = __fadd_rn(__fadd_rn(__fadd_rn(pd[0], pd[1]), __fadd_rn(pd[2], pd[3])),
                              __fadd_rn(__fadd_rn(pd[4], pd[5]), __fadd_rn(pd[6], pd[7])));
        res = __fadd_rn(res, pd[8]);
        res = __fadd_rn(res, pd[9]);
        ps[i] = res;
    }

    int rnk[SAMPLE_NUM];
#pragma unroll
    for (int j = 0; j < SAMPLE_NUM; ++j) {
        int r = 0;
#pragma unroll
        for (int m = 0; m < SAMPLE_NUM; ++m)
            r += (ps[m] < ps[j] || (ps[m] == ps[j] && m < j)) ? 1 : 0;
        rnk[j] = r;
    }

    float csx = 0.f, csy = 0.f, csz = 0.f;
    for (int r = 0; r < SELN; ++r) {
#pragma unroll
        for (int j = 0; j < SAMPLE_NUM; ++j) {
            if (rnk[j] == r) {
                csx = __fadd_rn(csx, clx[j]);
                csy = __fadd_rn(csy, cly[j]);
                csz = __fadd_rn(csz, clz[j]);
            }
        }
    }
    const float ccx = __fdiv_rn(csx, 7.0f);
    const float ccy = __fdiv_rn(csy, 7.0f);
    const float ccz = __fdiv_rn(csz, 7.0f);

    const float nx = centers[(size_t)bs * 3 + 0];
    const float ny = centers[(size_t)bs * 3 + 1];
    const float nz = centers[(size_t)bs * 3 + 2];

    const float ref_norm = __fsqrt_rn(__fadd_rn(
        __fadd_rn(__fmul_rn(nx, nx), __fmul_rn(ny, ny)), __fmul_rn(nz, nz)));
    const float den = __fadd_rn(ref_norm, 1e-4f);
    const float ux = __fdiv_rn(nx, den), uy = __fdiv_rn(ny, den), uz = __fdiv_rn(nz, den);
    const float ix = __fadd_rn(__fmul_rn(RADIUS, ux), nx);
    const float iy = __fadd_rn(__fmul_rn(RADIUS, uy), ny);
    const float iz = __fadd_rn(__fmul_rn(RADIUS, uz), nz);

    const float crvx = __fsub_rn(nx, ccx), crvy = __fsub_rn(ny, ccy), crvz = __fsub_rn(nz, ccz);
    const float crd = __fsqrt_rn(__fadd_rn(
        __fadd_rn(__fmul_rn(crvx, crvx), __fmul_rn(crvy, crvy)), __fmul_rn(crvz, crvz)));
    const float civx = __fsub_rn(ix, ccx), civy = __fsub_rn(iy, ccy), civz = __fsub_rn(iz, ccz);
    const float cid = __fsqrt_rn(__fadd_rn(
        __fadd_rn(__fmul_rn(civx, civx), __fmul_rn(civy, civy)), __fmul_rn(civz, civz)));
    const float dot = __fadd_rn(__fadd_rn(__fmul_rn(crvx, civx), __fmul_rn(crvy, civy)),
                                __fmul_rn(crvz, civz));
    const float ang_rci = __fdiv_rn(dot, __fadd_rn(__fmul_rn(crd, cid), 1e-6f));

    const float irvx = __fsub_rn(nx, ix), irvy = __fsub_rn(ny, iy), irvz = __fsub_rn(nz, iz);
    const float icvx = __fsub_rn(ccx, ix), icvy = __fsub_rn(ccy, iy), icvz = __fsub_rn(ccz, iz);
    const float dot2 = __fadd_rn(__fadd_rn(__fmul_rn(irvx, icvx), __fmul_rn(irvy, icvy)),
                                 __fmul_rn(irvz, icvz));
    const float ang_ric = __fdiv_rn(dot2, __fadd_rn(__fmul_rn(RADIUS, cid), 1e-6f));

    float* o = out + (size_t)bs * 5;
    o[0] = ref_norm;
    o[1] = crd;
    o[2] = cid;
    o[3] = ang_rci;
    o[4] = ang_ric;
}

// ---------------------------------------------------------------------------
extern "C" void kernel_launch(void* const* d_in, const int* in_sizes, int n_in,
                              void* d_out, int out_size, void* d_ws, size_t ws_size,
                              hipStream_t stream) {
    const float* xyz = (const float*)d_in[0];
    float* out = (float*)d_out;

    float* centers = (float*)d_ws;                       // B*NPOINT*3
    float* sx = centers + (size_t)BATCH * NPOINT * 3;    // B*N
    float* grouped = sx + (size_t)BATCH * NPTS;          // B*NPOINT*K*3

    static PermTab tab = build_tab();  // deterministic, host-only

    fps_kernel<<<BATCH, 1024, 0, stream>>>(xyz, centers, sx);
    knn_kernel<<<BATCH * NPOINT, 256, 0, stream>>>(xyz, centers, sx, grouped);
    feat_kernel<<<(BATCH * NPOINT + 255) / 256, 256, 0, stream>>>(centers, grouped, out, tab);
}